// Round 11
// baseline (140.167 us; speedup 1.0000x reference)
//
#include <hip/hip_runtime.h>
#include <math.h>

#define DET 512
#define NB  16
#define NT  180
#define PI_D 3.14159265358979323846
#define NPAIR 89
#define PADQ 108
#define NGP  45                  // interleaved pair-rows gp=0..44 (col gp | col 88-gp)
#define PKI_ROW 1536             // dwords per pair-row: 768 entries x 2 (T,U)
#define NOFF 101                 // off-diagonal transpose-pair units (a < bt)
#define NMRG 6                   // merged-diagonal blocks (2 diagonals each, a=4..15)
#define NBX  108                 // 101 off-diag + 6 merged-diag + 1 zeroer

// ws layout (bytes):
//   [0,8192)       (unused)
//   [TT,+512K)     (unused)
//   [XF0,+32K)     xf0[b][512]  f32   filtered row t=0
//   [XF90,+32K)    xf90[b][512] f32   filtered row t=90
//   [PK,+4.3M)     pki[b][gp][1536] u32  interleaved {T[i],U[i]} packed f16 pairs
// xT[b][t][512] f32 (5.9MB) lives in the OUTPUT buffer as scratch — backproj
// overwrites every out element afterward, so no extra ws needed.
#define TT_OFF   8192
#define XF0_OFF  (TT_OFF + 512*512*2)
#define XF90_OFF (XF0_OFF + 32768)
#define PK_OFF   (XF90_OFF + 32768)

typedef _Float16 half8  __attribute__((ext_vector_type(8)));
typedef _Float16 half4v __attribute__((ext_vector_type(4)));
typedef _Float16 half2v __attribute__((ext_vector_type(2)));
typedef float    float4v __attribute__((ext_vector_type(4)));

// f32 acc += f32 w * f16-half(pk)   (VOP3P mix, full-rate)
__device__ inline void fmix_lo(float& acc, float w, unsigned int pk) {
  asm("v_fma_mix_f32 %0, %1, %2, %0 op_sel_hi:[0,1,0]"
      : "+v"(acc) : "v"(w), "v"(pk));
}
__device__ inline void fmix_hi(float& acc, float w, unsigned int pk) {
  asm("v_fma_mix_f32 %0, %1, %2, %0 op_sel:[0,1,0] op_sel_hi:[0,1,0]"
      : "+v"(acc) : "v"(w), "v"(pk));
}

// ---------------- Transpose pre-pass: x[b][d][t] -> xT[b][t][d] ----------------
// Coalesced read (720B rows as float4) and write (256B segments). ~3 µs.
__global__ __launch_bounds__(256) void transpose_kernel(const float* __restrict__ x,
                                                        float* __restrict__ xT) {
  __shared__ float tile[64][181];
  int b = blockIdx.y, d0 = blockIdx.x * 64;
  int tid = threadIdx.x;
  const float* xb = x + ((size_t)b * DET + d0) * NT;
#pragma unroll
  for (int i = 0; i < 12; i++) {
    int idx = tid + 256 * i;                 // float4 index, 45 per d-row
    if (idx < 2880) {
      int d = idx / 45;
      int j = idx - d * 45;
      float4 v = *(const float4*)&xb[(size_t)d * NT + j * 4];
      tile[d][j * 4 + 0] = v.x; tile[d][j * 4 + 1] = v.y;
      tile[d][j * 4 + 2] = v.z; tile[d][j * 4 + 3] = v.w;
    }
  }
  __syncthreads();
  float* xTb = xT + (size_t)b * NT * DET + d0;
#pragma unroll
  for (int i = 0; i < 12; i++) {
    int t = (tid >> 4) + 16 * i;
    if (t < NT) {
      int c = (tid & 15) * 4;
      float4 v;
      v.x = tile[c + 0][t]; v.y = tile[c + 1][t];
      v.z = tile[c + 2][t]; v.w = tile[c + 3][t];
      *(float4*)&xTb[(size_t)t * DET + c] = v;
    }
  }
}

// ---------------- Filter (MFMA GEMM) + fused interleaved f16 pair-packing ----------------
// R11: x staged from transposed xT — 8 coalesced float4 loads/lane (2KB rows)
// instead of 32 scalar 4B loads at 720B stride. Conversion arithmetic identical.
__global__ __launch_bounds__(256) void filter_kernel(const float* __restrict__ xT,
                                                     char* __restrict__ wsb) {
  __shared__ _Float16 xs_h[16][512];
  __shared__ _Float16 xs_l[16][512];
  __shared__ float xfs[16][65];
  __shared__ _Float16 wls[8][1032];      // 8 shift-copies, 2064B row (16B-mult)
  unsigned int* pkg = (unsigned int*)(wsb + PK_OFF);

  int tid = threadIdx.x;
  int p = blockIdx.x, b = blockIdx.y;
  int dt0 = blockIdx.z * 2;

  // ---- fill Toeplitz shift-copies: thread fills 4 consecutive k for each r ----
  {
    int k0 = tid * 4;
    const float CSC = (float)(-2048.0 / (PI_D * PI_D));   // (w*1024) numerator
#pragma unroll
    for (int r = 0; r < 8; r++) {
      half4v v;
#pragma unroll
      for (int j = 0; j < 4; j++) {
        int delta = 511 - (k0 + j) - r;
        float wv;
        if (delta == 0) wv = 512.0f;                       // 0.5 * 1024
        else if (delta & 1) wv = CSC / (float)(delta * delta);
        else wv = 0.0f;
        v[j] = (_Float16)wv;
      }
      *(half4v*)&wls[r][k0] = v;
    }
  }

  // ---- stage x: 8 passes, 2 t-rows each, coalesced float4 from xT ----
  {
    int rowp = tid >> 7;                    // wave-pair uniform
    int k0 = (tid & 127) * 4;
    int c0 = k0 >> 3, h0 = k0 & 7;          // h0 in {0,4}
    const float* xTb = xT + (size_t)b * NT * DET;
#pragma unroll
    for (int pass = 0; pass < 8; pass++) {
      int m = pass * 2 + rowp;
      int tS;
      if (p < 11) tS = (m < 8) ? (8 * p + 1 + m) : (164 - 8 * p + m);
      else        tS = (m == 0) ? 89 : ((m == 1) ? 91 : ((m == 3) ? 90 : 0));
      float4 v = *(const float4*)&xTb[(size_t)tS * DET + k0];
      int phys = (((c0 ^ (m & 7)) << 3) | h0);
      _Float16 a0 = (_Float16)v.x, a1 = (_Float16)v.y;
      _Float16 a2 = (_Float16)v.z, a3 = (_Float16)v.w;
      half4v hv = {a0, a1, a2, a3};
      half4v lv = {(_Float16)(v.x - (float)a0), (_Float16)(v.y - (float)a1),
                   (_Float16)(v.z - (float)a2), (_Float16)(v.w - (float)a3)};
      *(half4v*)&xs_h[m][phys] = hv;
      *(half4v*)&xs_l[m][phys] = lv;
    }
  }
  __syncthreads();   // covers xs staging AND wls fill

  int nprb = (p < 11) ? 8 : 1;
  int tpb0 = (p < 11) ? 8 * p : 88;
  if (blockIdx.z == 0) {
    // zero pad entries [0,108) and [620,768) for both slots (uint2 per entry)
    int idx = (tid < 108) ? tid : (620 + (tid - 108));
    uint2 z2; z2.x = 0u; z2.y = 0u;
    for (int pr = 0; pr < nprb; pr++) {
      int tq = (p < 11) ? (tpb0 + pr) : 88;
      int gp = (tq <= 44) ? tq : 88 - tq;
      *(uint2*)&pkg[((size_t)b * NGP + gp) * PKI_ROW + 2 * idx] = z2;
    }
  }

  int lane = tid & 63, wv = tid >> 6;
  int mm = lane & 15, q = lane >> 4;
  const _Float16* arh = &xs_h[mm][0];
  const _Float16* arl = &xs_l[mm][0];
  int e = mm & 7;
  int mp = tid >> 5, cc = (tid & 31) * 2;
  int rT = (p < 11) ? mp : 0;
  int rU = (p < 11) ? (15 - mp) : 1;
  int tpp = (p < 11) ? (8 * p + mp) : 88;
  bool dopack = (p < 11) || (mp == 0);
  int gp_  = (tpp <= 44) ? tpp : 88 - tpp;
  int slot = (tpp <= 44) ? 0 : 1;

  for (int dti = 0; dti < 2; dti++) {
    int dt = dt0 + dti;
    int dw = dt * 64 + wv * 16 + mm;
    int sdw = 511 - dw;
    const _Float16* thl = &wls[sdw & 7][sdw & ~7];   // 16B-aligned per-lane base
    float4v acc0 = {0.f, 0.f, 0.f, 0.f};
    float4v acc1 = {0.f, 0.f, 0.f, 0.f};
#pragma unroll 4
    for (int kc = 0; kc < 512; kc += 32) {
      int ph = ((((kc >> 3) + q) ^ e) << 3);
      half8 Ah = *(const half8*)&arh[ph];
      half8 Al = *(const half8*)&arl[ph];
      half8 Bh = *(const half8*)&thl[kc + q * 8];
      acc0 = __builtin_amdgcn_mfma_f32_16x16x32_f16(Ah, Bh, acc0, 0, 0, 0);
      acc1 = __builtin_amdgcn_mfma_f32_16x16x32_f16(Al, Bh, acc1, 0, 0, 0);
    }
    if (dti > 0) __syncthreads();
#pragma unroll
    for (int i = 0; i < 4; i++)
      xfs[q * 4 + i][wv * 16 + mm] = (acc0[i] + acc1[i]) * 0.0009765625f;
    __syncthreads();
    if (dopack) {
      float ft0 = xfs[rT][cc], ft1 = xfs[rT][cc + 1];
      float fu0 = xfs[rU][cc], fu1 = xfs[rU][cc + 1];
      auto p0 = __builtin_amdgcn_cvt_pkrtz(ft0, fu0);   // lo=ft, hi=fu
      auto p1 = __builtin_amdgcn_cvt_pkrtz(ft1, fu1);
      unsigned int w0, w1;
      __builtin_memcpy(&w0, &p0, 4);
      __builtin_memcpy(&w1, &p1, 4);
      unsigned int* row = pkg + ((size_t)b * NGP + gp_) * PKI_ROW;
      int en = PADQ + dt * 64 + cc;
      row[2 * en + slot]     = w0;
      row[2 * en + 2 + slot] = w1;
      if (tpp == 44) {               // self-paired row: duplicate into slot 1
        row[2 * en + 1] = w0;
        row[2 * en + 3] = w1;
      }
    }
    if (p == 11 && tid < 64) {         // singles: row2=t0, row3=t90
      float* f0  = (float*)(wsb + XF0_OFF)  + (size_t)b * DET;
      float* f90 = (float*)(wsb + XF90_OFF) + (size_t)b * DET;
      f0[dt * 64 + tid]  = xfs[2][tid];
      f90[dt * 64 + tid] = xfs[3][tid];
    }
  }
}

// ---------------- Backprojection v16: uniform-weight blocks (R10, unchanged) ----------------
#define PROCESS(c_, s_, SW)                                                    \
  {                                                                            \
    float inner = fmaf(-(s_), q_, 363.5f);                                     \
    float iyA = fmaf( (c_), p_, inner);                                        \
    float iyB = fmaf(-(c_), p_, inner);                                        \
    int   iA = (int)iyA;  float wA = __builtin_amdgcn_fractf(iyA);             \
    int   iB = (int)iyB;  float wB = __builtin_amdgcn_fractf(iyB);             \
    float vA = 1.f - wA, vB = 1.f - wB;                                        \
    uint4 rA, rB, rMA, rMB;                                                    \
    __builtin_memcpy(&rA,  &colI[2 * iA], 16);                                 \
    __builtin_memcpy(&rB,  &colI[2 * iB], 16);                                 \
    __builtin_memcpy(&rMA, &colI[2 * (726 - iA)], 16);                         \
    __builtin_memcpy(&rMB, &colI[2 * (726 - iB)], 16);                         \
    unsigned tA0 = SW ? rA.y : rA.x,  tA1 = SW ? rA.w : rA.z;                  \
    unsigned uA0 = SW ? rA.x : rA.y,  uA1 = SW ? rA.z : rA.w;                  \
    unsigned tB0 = SW ? rB.y : rB.x,  tB1 = SW ? rB.w : rB.z;                  \
    unsigned uB0 = SW ? rB.x : rB.y,  uB1 = SW ? rB.z : rB.w;                  \
    unsigned tMA0 = SW ? rMA.y : rMA.x,  tMA1 = SW ? rMA.w : rMA.z;            \
    unsigned uMA0 = SW ? rMA.x : rMA.y,  uMA1 = SW ? rMA.z : rMA.w;            \
    unsigned tMB0 = SW ? rMB.y : rMB.x,  tMB1 = SW ? rMB.w : rMB.z;            \
    unsigned uMB0 = SW ? rMB.x : rMB.y,  uMB1 = SW ? rMB.z : rMB.w;            \
    fmix_lo(A1, vA, tA0);  fmix_lo(A1, wA, tA1);                               \
    fmix_hi(A1, vB, tB0);  fmix_hi(A1, wB, tB1);                               \
    fmix_lo(A2, vB, tB0);  fmix_lo(A2, wB, tB1);                               \
    fmix_hi(A2, vA, tA0);  fmix_hi(A2, wA, tA1);                               \
    fmix_lo(A3, wA, tMA0); fmix_lo(A3, vA, tMA1);                              \
    fmix_hi(A3, wB, tMB0); fmix_hi(A3, vB, tMB1);                              \
    fmix_lo(A4, wB, tMB0); fmix_lo(A4, vB, tMB1);                              \
    fmix_hi(A4, wA, tMA0); fmix_hi(A4, vA, tMA1);                              \
    fmix_lo(B1, wA, uMA0); fmix_lo(B1, vA, uMA1);                              \
    fmix_hi(B1, vB, uB0);  fmix_hi(B1, wB, uB1);                               \
    fmix_lo(B2, wB, uMB0); fmix_lo(B2, vB, uMB1);                              \
    fmix_hi(B2, vA, uA0);  fmix_hi(B2, wA, uA1);                               \
    fmix_lo(B3, vA, uA0);  fmix_lo(B3, wA, uA1);                               \
    fmix_hi(B3, wB, uMB0); fmix_hi(B3, vB, uMB1);                              \
    fmix_lo(B4, vB, uB0);  fmix_lo(B4, wB, uB1);                               \
    fmix_hi(B4, wA, uMA0); fmix_hi(B4, vA, uMA1);                              \
  }

#define PROCESSP(c_, s_, SW, pp, qq, AA1, AA2, AA3, AA4)                       \
  {                                                                            \
    float inner = fmaf(-(s_), (qq), 363.5f);                                   \
    float iyA = fmaf( (c_), (pp), inner);                                      \
    float iyB = fmaf(-(c_), (pp), inner);                                      \
    int   iA = (int)iyA;  float wA = __builtin_amdgcn_fractf(iyA);             \
    int   iB = (int)iyB;  float wB = __builtin_amdgcn_fractf(iyB);             \
    float vA = 1.f - wA, vB = 1.f - wB;                                        \
    uint4 rA, rB, rMA, rMB;                                                    \
    __builtin_memcpy(&rA,  &colI[2 * iA], 16);                                 \
    __builtin_memcpy(&rB,  &colI[2 * iB], 16);                                 \
    __builtin_memcpy(&rMA, &colI[2 * (726 - iA)], 16);                         \
    __builtin_memcpy(&rMB, &colI[2 * (726 - iB)], 16);                         \
    unsigned tA0 = SW ? rA.y : rA.x,  tA1 = SW ? rA.w : rA.z;                  \
    unsigned tB0 = SW ? rB.y : rB.x,  tB1 = SW ? rB.w : rB.z;                  \
    unsigned tMA0 = SW ? rMA.y : rMA.x,  tMA1 = SW ? rMA.w : rMA.z;            \
    unsigned tMB0 = SW ? rMB.y : rMB.x,  tMB1 = SW ? rMB.w : rMB.z;            \
    fmix_lo(AA1, vA, tA0);  fmix_lo(AA1, wA, tA1);                             \
    fmix_hi(AA1, vB, tB0);  fmix_hi(AA1, wB, tB1);                             \
    fmix_lo(AA2, vB, tB0);  fmix_lo(AA2, wB, tB1);                             \
    fmix_hi(AA2, vA, tA0);  fmix_hi(AA2, wA, tA1);                             \
    fmix_lo(AA3, wA, tMA0); fmix_lo(AA3, vA, tMA1);                            \
    fmix_hi(AA3, wB, tMB0); fmix_hi(AA3, vB, tMB1);                            \
    fmix_lo(AA4, wB, tMB0); fmix_lo(AA4, vB, tMB1);                            \
    fmix_hi(AA4, wA, tMA0); fmix_hi(AA4, vA, tMA1);                            \
  }

__global__ __launch_bounds__(256, 8) void backproj_kernel(
    const char* __restrict__ wsb, float* __restrict__ out) {
  __shared__ unsigned int pk[2][PKI_ROW];   // 12288 B; epilogue-aliased as qs
  __shared__ float2 trigs[48];
  int tid = threadIdx.x;
  int b   = blockIdx.y;
  int bx  = blockIdx.x;
  int lx = tid & 15, ly = tid >> 4;
  float* ob = out + (size_t)b * DET * DET;
  int w = tid >> 6, l = tid & 63;

  if (bx == NOFF + NMRG) {
    // zero dead 16x16 tiles (a, bt<L[a]) and their 3 mirrors
    const int LDEAD[10] = {10,8,6,5,4,3,2,2,1,1};
    for (int a = 0; a < 10; a++)
      for (int bt = 0; bt < LDEAD[a]; bt++) {
        int X1 = 16*a + lx, X2 = 511 - X1;
        int Y1 = 16*bt + ly, Y2 = 511 - Y1;
        ob[(size_t)Y1*DET + X1] = 0.f;
        ob[(size_t)Y1*DET + X2] = 0.f;
        ob[(size_t)Y2*DET + X1] = 0.f;
        ob[(size_t)Y2*DET + X2] = 0.f;
      }
    return;
  }

  // pair trig: (cos t, sin t), t = tid+1 degrees
  if (tid < NGP) {
    float th = (float)(tid + 1) * (float)(PI_D / 180.0);
    float2 cs; cs.x = cosf(th); cs.y = sinf(th);
    trigs[tid] = cs;
  }

  const unsigned int* pkg = (const unsigned int*)(wsb + PK_OFF) + (size_t)b * NGP * PKI_ROW;

  // stage pair-row gp (6144 B): 6 chunks of 1024B over 4 waves (16B/lane DMA)
  auto stage_group = [&](int g, int par) {
    {
      const unsigned int* src = pkg + (size_t)g * PKI_ROW + w * 256 + l * 4;
      char* dst = (char*)&pk[par][0] + w * 1024;
      __builtin_amdgcn_global_load_lds(
          (const __attribute__((address_space(1))) unsigned int*)src,
          (__attribute__((address_space(3))) unsigned int*)dst, 16, 0, 0);
    }
    if (w < 2) {
      const unsigned int* src = pkg + (size_t)g * PKI_ROW + (w + 4) * 256 + l * 4;
      char* dst = (char*)&pk[par][0] + (w + 4) * 1024;
      __builtin_amdgcn_global_load_lds(
          (const __attribute__((address_space(1))) unsigned int*)src,
          (__attribute__((address_space(3))) unsigned int*)dst, 16, 0, 0);
    }
  };

  const float* f0  = (const float*)(wsb + XF0_OFF)  + (size_t)b * DET;
  const float* f90 = (const float*)(wsb + XF90_OFF) + (size_t)b * DET;
  const float SC = (float)(PI_D / 360.0);

  if (bx >= NOFF) {
    // ---- merged-diagonal block: two diagonal tiles (a1,a1),(a2,a2), P-only ----
    int d = bx - NOFF;
    int a1 = 4 + 2 * d, a2 = 5 + 2 * d;
    float p1_ = (float)(16 * a1 + lx) - 255.5f, q1_ = (float)(16 * a1 + ly) - 255.5f;
    float p2_ = (float)(16 * a2 + lx) - 255.5f, q2_ = (float)(16 * a2 + ly) - 255.5f;
    int mk1 = 481 - 32 * a1, mn1 = 505 - 32 * a1 - 8 * w;
    int mk2 = 481 - 32 * a2, mn2 = 505 - 32 * a2 - 8 * w;
    bool wl1 = (mk1 * mk1 + mn1 * mn1 <= 261632);
    bool wl2 = (mk2 * mk2 + mn2 * mn2 <= 261632);

    float A1=0.f, A2=0.f, A3=0.f, A4=0.f;   // tile a1
    float C1=0.f, C2=0.f, C3=0.f, C4=0.f;   // tile a2

    stage_group(0, 0);
    __syncthreads();
    for (int g = 0; g < NGP; g++) {
      if (g + 1 < NGP) stage_group(g + 1, (g + 1) & 1);
      float2 cs = trigs[g];
      const unsigned int* colI = &pk[g & 1][0];
      if (wl1) {
        PROCESSP(cs.x, cs.y, 0, p1_, q1_, A1, A2, A3, A4);
        if (g != 44) PROCESSP(cs.y, cs.x, 1, p1_, q1_, A1, A2, A3, A4);
      }
      if (wl2) {
        PROCESSP(cs.x, cs.y, 0, p2_, q2_, C1, C2, C3, C4);
        if (g != 44) PROCESSP(cs.y, cs.x, 1, p2_, q2_, C1, C2, C3, C4);
      }
      __syncthreads();
    }
#pragma unroll
    for (int t = 0; t < 2; t++) {
      int a = t ? a2 : a1;
      int X1 = 16 * a + lx, X2 = 511 - X1;
      int Y1 = 16 * a + ly, Y2 = 511 - Y1;
      int kx = 2 * X1 - 511, ky = 2 * Y1 - 511;
      bool in = (kx * kx + ky * ky) <= 261632;
      float g0x1 = f0[X1], g0x2 = f0[X2];
      float g90y1 = f90[Y1], g90y2 = f90[Y2];
      float P1 = (t ? C1 : A1) + g0x1 + g90y2;
      float P2 = (t ? C2 : A2) + g0x2 + g90y2;
      float P3 = (t ? C3 : A3) + g0x2 + g90y1;
      float P4 = (t ? C4 : A4) + g0x1 + g90y1;
      ob[(size_t)Y1 * DET + X1] = in ? P1 * SC : 0.f;
      ob[(size_t)Y1 * DET + X2] = in ? P2 * SC : 0.f;
      ob[(size_t)Y2 * DET + X2] = in ? P3 * SC : 0.f;
      ob[(size_t)Y2 * DET + X1] = in ? P4 * SC : 0.f;
    }
    return;
  }

  // ---- off-diagonal unit (a < bt): P-quad + transposed Q-quad ----
  int a = (bx>=6)+(bx>=14)+(bx>=24)+(bx>=35)+(bx>=46)+(bx>=56)+(bx>=65)
        + (bx>=73)+(bx>=80)+(bx>=86)+(bx>=91)+(bx>=95)+(bx>=98)+(bx>=100);
  int Sa, bs;
  if (a < 8) { Sa = (int)((0x41382E23180E0600ULL >> (8*a)) & 0xFF);
               bs = (int)((0x080706050506080AULL >> (8*a)) & 0xFF); }
  else       { Sa = (int)((0x0064625F5B565049ULL >> (8*(a-8))) & 0xFF);
               bs = (int)((0x000F0E0D0C0B0A09ULL >> (8*(a-8))) & 0xFF); }
  int bt = bx - Sa + bs;
  int tx = 16*a, ty = 16*bt;

  int X1 = tx + lx, X2 = 511 - X1;
  int Y1 = ty + ly, Y2 = 511 - Y1;
  float p_ = (float)X1 - 255.5f;
  float q_ = (float)Y1 - 255.5f;

  int mkx = 481 - 32*a;
  int mky = 505 - 32*bt - 8*w;          // min |ky| over this wave's 4 rows
  bool wlive = (mkx*mkx + mky*mky <= 261632);   // symmetric: covers P and Q sets

  float A1=0.f, A2=0.f, A3=0.f, A4=0.f;   // P-tile mirrors
  float B1=0.f, B2=0.f, B3=0.f, B4=0.f;   // Q (transposed) tile mirrors

  stage_group(0, 0);
  __syncthreads();   // covers stage(0) AND trigs fill

  for (int g = 0; g < NGP; g++) {
    if (g + 1 < NGP) stage_group(g + 1, (g + 1) & 1);
    float2 cs = trigs[g];
    const unsigned int* colI = &pk[g & 1][0];
    if (wlive) {
      PROCESS(cs.x, cs.y, 0);                    // tp = g      (P=slot0, Q=slot1)
      if (g != 44) PROCESS(cs.y, cs.x, 1);       // tp = 88-g   (P=slot1, Q=slot0)
    }
    __syncthreads();
  }

  // epilogue: singles t=0 / t=90, mask, scale
  int kx = 2*X1 - 511, ky = 2*Y1 - 511;
  bool in = (kx*kx + ky*ky) <= 261632;            // symmetric across all 8 outputs

  float g0x1 = f0[X1], g0x2 = f0[X2];
  float g90y1 = f90[Y1], g90y2 = f90[Y2];
  float P1 = A1 + g0x1 + g90y2;
  float P2 = A2 + g0x2 + g90y2;
  float P3 = A3 + g0x2 + g90y1;
  float P4 = A4 + g0x1 + g90y1;
  ob[(size_t)Y1*DET + X1] = in ? P1*SC : 0.f;
  ob[(size_t)Y1*DET + X2] = in ? P2*SC : 0.f;
  ob[(size_t)Y2*DET + X2] = in ? P3*SC : 0.f;
  ob[(size_t)Y2*DET + X1] = in ? P4*SC : 0.f;

  {
    float g0y1 = f0[Y1], g0y2 = f0[Y2];
    float g90x1 = f90[X1], g90x2 = f90[X2];
    float Q1 = B1 + g0y1 + g90x2;
    float Q2 = B2 + g0y1 + g90x1;
    float Q3 = B3 + g0y2 + g90x1;
    float Q4 = B4 + g0y2 + g90x2;
    Q1 = in ? Q1*SC : 0.f;
    Q2 = in ? Q2*SC : 0.f;
    Q3 = in ? Q3*SC : 0.f;
    Q4 = in ? Q4*SC : 0.f;
    __syncthreads();                                // pk free now
    float* qs = (float*)&pk[0][0];                  // [4][16][17] padded
    qs[(0*16 + lx)*17 + ly] = Q1;
    qs[(1*16 + lx)*17 + ly] = Q2;
    qs[(2*16 + lx)*17 + ly] = Q3;
    qs[(3*16 + lx)*17 + ly] = Q4;
    __syncthreads();
    float o1 = qs[(0*16 + ly)*17 + lx];
    float o2 = qs[(1*16 + ly)*17 + lx];
    float o3 = qs[(2*16 + ly)*17 + lx];
    float o4 = qs[(3*16 + ly)*17 + lx];
    int r1 = tx + ly, r2 = 511 - r1;
    int c1 = ty + lx, c2 = 511 - c1;
    ob[(size_t)r1*DET + c1] = o1;   // Q1: rows X1, cols Y1
    ob[(size_t)r2*DET + c1] = o2;   // Q2: rows X2, cols Y1
    ob[(size_t)r2*DET + c2] = o3;   // Q3: rows X2, cols Y2
    ob[(size_t)r1*DET + c2] = o4;   // Q4: rows X1, cols Y2
  }
}

extern "C" void kernel_launch(void* const* d_in, const int* in_sizes, int n_in,
                              void* d_out, int out_size, void* d_ws, size_t ws_size,
                              hipStream_t stream) {
  (void)in_sizes; (void)n_in; (void)out_size; (void)ws_size;
  const float* x = (const float*)d_in[0];
  float* out = (float*)d_out;
  char*  wsb = (char*)d_ws;
  float* xT = out;   // scratch: xT[16][180][512] f32 = 5.9MB < 16.8MB out;
                     // backproj overwrites every out element afterward.

  transpose_kernel<<<dim3(8, NB), 256, 0, stream>>>(x, xT);
  filter_kernel<<<dim3(12, 16, 4), 256, 0, stream>>>(xT, wsb);
  backproj_kernel<<<dim3(NBX, NB), 256, 0, stream>>>(wsb, out);
}